// Round 10
// baseline (4989.926 us; speedup 1.0000x reference)
//
#include <hip/hip_runtime.h>
#include <hip/hip_bf16.h>
#include <hip/hip_fp16.h>
#include <type_traits>

#define N_NODES 50000
#define N_EDGES 600000
#define H 128

// ---------------- workspace layout (word offsets), ea LAST --------
constexpr size_t W_H1  = 6400000;
constexpr size_t W_RP  = 12800000;
constexpr size_t W_CUR = 12850004;
constexpr size_t W_CE  = 12900004;
constexpr size_t W_CS  = 13500004;
constexpr size_t W_EA  = 14100004;                       // *4B (16B aligned)
constexpr size_t NEED32 = (W_EA + (size_t)N_EDGES * H) * 4;        // 363.6 MB
constexpr size_t NEED16 = (W_EA + (size_t)N_EDGES * H / 2) * 4;    // 210.0 MB

// ---------------- CSR build ----------------
__global__ void count_kernel(const int* __restrict__ ei, int* __restrict__ cnt) {
    int e = blockIdx.x * blockDim.x + threadIdx.x;
    if (e < N_EDGES) atomicAdd(&cnt[ei[N_EDGES + e]], 1);
}

__global__ void scan_kernel(int* __restrict__ cursor, int* __restrict__ row_ptr) {
    __shared__ int wsum[16];
    __shared__ int wexc[16];
    __shared__ int s_total;
    const int t = threadIdx.x;
    const int lane = t & 63, wid = t >> 6;
    int carry = 0;
    if (t == 0) row_ptr[0] = 0;
    for (int base = 0; base < N_NODES; base += 1024) {
        int i = base + t;
        int v = (i < N_NODES) ? cursor[i] : 0;
        int x = v;
#pragma unroll
        for (int off = 1; off < 64; off <<= 1) {
            int y = __shfl_up(x, off, 64);
            if (lane >= off) x += y;
        }
        if (lane == 63) wsum[wid] = x;
        __syncthreads();
        if (wid == 0 && lane < 16) {
            int w = wsum[lane];
            int xs = w;
#pragma unroll
            for (int off = 1; off < 16; off <<= 1) {
                int y = __shfl_up(xs, off, 64);
                if (lane >= off) xs += y;
            }
            wexc[lane] = xs - w;
            if (lane == 15) s_total = xs;
        }
        __syncthreads();
        int incl = carry + wexc[wid] + x;
        if (i < N_NODES) {
            cursor[i] = incl - v;
            row_ptr[i + 1] = incl;
        }
        carry += s_total;
        __syncthreads();
    }
}

__global__ void fill_kernel(const int* __restrict__ ei, int* __restrict__ cursor,
                            int* __restrict__ col_e, int* __restrict__ col_s) {
    int e = blockIdx.x * blockDim.x + threadIdx.x;
    if (e < N_EDGES) {
        int d = ei[N_EDGES + e];
        int pos = atomicAdd(&cursor[d], 1);
        col_e[pos] = e;
        col_s[pos] = ei[e];
    }
}

// ---------------- GEMM core: 64 rows x 128 cols, K staged in 32-row quarters ----------
// a_lds: [64][128] (32KB); w_lds: [32][128] (16KB). Total 48KB -> 3 blocks/CU.
// Thread (tx=t&31 -> cols tx*4..+3, ty=t>>5 in 0..7 -> rows ty*8..+7), acc[8][4].
// Round-9 fix: 8 rows/thread halves W-side LDS reads per FMA (was LDS-co-bound at 55% VALU).
__device__ __forceinline__ void mm_q(const float* __restrict__ a_lds,
                                     const float* __restrict__ w_lds,
                                     int tx, int ty, int k0, float acc[8][4]) {
#pragma unroll
    for (int k = 0; k < 32; k += 4) {
        float4 av[8], wv[4];
#pragma unroll
        for (int rr = 0; rr < 8; ++rr)
            av[rr] = *(const float4*)&a_lds[(ty * 8 + rr) * H + k0 + k];
#pragma unroll
        for (int kk = 0; kk < 4; ++kk)
            wv[kk] = *(const float4*)&w_lds[(k + kk) * H + tx * 4];
#pragma unroll
        for (int rr = 0; rr < 8; ++rr) {
#pragma unroll
            for (int kk = 0; kk < 4; ++kk) {
                float a = ((const float*)&av[rr])[kk];
                acc[rr][0] = fmaf(a, ((const float*)&wv[kk])[0], acc[rr][0]);
                acc[rr][1] = fmaf(a, ((const float*)&wv[kk])[1], acc[rr][1]);
                acc[rr][2] = fmaf(a, ((const float*)&wv[kk])[2], acc[rr][2]);
                acc[rr][3] = fmaf(a, ((const float*)&wv[kk])[3], acc[rr][3]);
            }
        }
    }
}

// stage 32 rows (16KB) of a [128-col] weight matrix into w_lds (4 float4/thread)
__device__ __forceinline__ void stage_wq(const float* __restrict__ wsrc,
                                         float* __restrict__ w_lds, int t) {
#pragma unroll
    for (int i = 0; i < 4; ++i)
        *(float4*)&w_lds[t * 4 + i * 1024] = *(const float4*)&wsrc[t * 4 + i * 1024];
}

// LayerNorm over one row spread across a 32-lane tx group (4 vals/lane).
// xor masks 1..16 keep lanes within their 32-lane half; call UNCONDITIONALLY.
__device__ __forceinline__ float4 ln_vals(float v0, float v1, float v2, float v3,
                                          int tx, const float* __restrict__ g,
                                          const float* __restrict__ be) {
    float sum = v0 + v1 + v2 + v3;
    float sq = v0 * v0 + v1 * v1 + v2 * v2 + v3 * v3;
#pragma unroll
    for (int m = 1; m < 32; m <<= 1) {
        sum += __shfl_xor(sum, m, 64);
        sq  += __shfl_xor(sq, m, 64);
    }
    float mean = sum * 0.0078125f;
    float var = sq * 0.0078125f - mean * mean;
    float rstd = rsqrtf(var + 1e-5f);
    float4 gv = *(const float4*)&g[tx * 4];
    float4 bv = *(const float4*)&be[tx * 4];
    float4 o;
    o.x = (v0 - mean) * rstd * gv.x + bv.x;
    o.y = (v1 - mean) * rstd * gv.y + bv.y;
    o.z = (v2 - mean) * rstd * gv.z + bv.z;
    o.w = (v3 - mean) * rstd * gv.w + bv.w;
    return o;
}

// ---------------- encoder: OUT = LN(relu(in@w1+b1)@w2+b2) ----------------
template <int IN_DIM, typename OUT_T>
__global__ __launch_bounds__(256, 3) void encoder_kernel(
    const float* __restrict__ in, const float* __restrict__ w1,
    const float* __restrict__ b1, const float* __restrict__ w2,
    const float* __restrict__ b2, const float* __restrict__ g,
    const float* __restrict__ be, OUT_T* __restrict__ out,
    int nrows) {
    __shared__ float w_lds[32 * H];
    __shared__ float a_lds[64 * H];
    const int t = threadIdx.x;
    const int row0 = blockIdx.x * 64;

    stage_wq(w2, w_lds, t);             // w2 rows 0..31

    // hidden stage: column-per-thread (conflict-free LDS writes), 32 rows/thread
    {
        const int c = t & 127;
        const int rh = (t >> 7) * 32;
        const float bb1 = b1[c];
        float w1r[IN_DIM];
#pragma unroll
        for (int i = 0; i < IN_DIM; ++i)
            w1r[i] = w1[i * H + c];
#pragma unroll 4
        for (int rr = 0; rr < 32; ++rr) {
            int r = rh + rr;
            int grow = row0 + r;
            float acc = bb1;
            if (grow < nrows) {
#pragma unroll
                for (int i = 0; i < IN_DIM; ++i)
                    acc = fmaf(in[(size_t)grow * IN_DIM + i], w1r[i], acc);
            }
            a_lds[r * H + c] = fmaxf(acc, 0.f);
        }
    }
    __syncthreads();

    const int tx = t & 31, ty = t >> 5;
    float acc[8][4] = {};
    mm_q(a_lds, w_lds, tx, ty, 0, acc);
#pragma unroll
    for (int q = 1; q < 4; ++q) {
        __syncthreads();
        stage_wq(w2 + q * 32 * H, w_lds, t);
        __syncthreads();
        mm_q(a_lds, w_lds, tx, ty, q * 32, acc);
    }

    float4 bb = *(const float4*)&b2[tx * 4];
#pragma unroll
    for (int rr = 0; rr < 8; ++rr) {
        int gr = row0 + ty * 8 + rr;
        float4 o = ln_vals(acc[rr][0] + bb.x, acc[rr][1] + bb.y,
                           acc[rr][2] + bb.z, acc[rr][3] + bb.w, tx, g, be);
        if (gr < nrows) {
            if constexpr (std::is_same<OUT_T, float>::value) {
                *(float4*)(out + (size_t)gr * H + tx * 4) = o;
            } else {
                __half2* dp = (__half2*)(out + (size_t)gr * H + tx * 4);
                dp[0] = __floats2half2_rn(o.x, o.y);
                dp[1] = __floats2half2_rn(o.z, o.w);
            }
        }
    }
}

// ---------------- fused GINEConv layer ----------------
// a = h_in + sum_in relu(h_in[src]+ea[e]);  hid = relu(a@w1+b1) (in LDS)
// h_out = LN(h_in + relu(hid@w2+b2))
template <typename EA_T>
__global__ __launch_bounds__(256, 3) void conv_kernel(
    const float* __restrict__ h_in, const EA_T* __restrict__ ea,
    const int* __restrict__ row_ptr, const int* __restrict__ col_e,
    const int* __restrict__ col_s,
    const float* __restrict__ w1, const float* __restrict__ b1,
    const float* __restrict__ w2, const float* __restrict__ b2,
    const float* __restrict__ g, const float* __restrict__ be,
    float* __restrict__ h_out, int nrows) {
    __shared__ float w_lds[32 * H];
    __shared__ float a_lds[64 * H];
    const int t = threadIdx.x;
    const int row0 = blockIdx.x * 64;

    stage_wq(w1, w_lds, t);             // w1 rows 0..31

    // gather: 8 nodes per pass (32 lanes x float4 per node), 8 passes
    const int j = (t & 31) * 4;
    for (int pass = 0; pass < 8; ++pass) {
        int r = pass * 8 + (t >> 5);
        int n = row0 + r;
        float ax = 0.f, ay = 0.f, az = 0.f, aw = 0.f;
        if (n < nrows) {
            int beg = row_ptr[n], end = row_ptr[n + 1];
            for (int p = beg; p < end; ++p) {
                int e = col_e[p];
                int s = col_s[p];
                float4 hv = *(const float4*)&h_in[s * H + j];
                float ex, ey, ez, ew;
                if constexpr (std::is_same<EA_T, float>::value) {
                    float4 ev = *(const float4*)(ea + (size_t)e * H + j);
                    ex = ev.x; ey = ev.y; ez = ev.z; ew = ev.w;
                } else {
                    const __half2* ep = (const __half2*)(ea + (size_t)e * H + j);
                    float2 e01 = __half22float2(ep[0]);
                    float2 e23 = __half22float2(ep[1]);
                    ex = e01.x; ey = e01.y; ez = e23.x; ew = e23.y;
                }
                ax += fmaxf(hv.x + ex, 0.f);
                ay += fmaxf(hv.y + ey, 0.f);
                az += fmaxf(hv.z + ez, 0.f);
                aw += fmaxf(hv.w + ew, 0.f);
            }
            float4 hn = *(const float4*)&h_in[n * H + j];
            ax += hn.x; ay += hn.y; az += hn.z; aw += hn.w;
        }
        float4 o = {ax, ay, az, aw};
        *(float4*)&a_lds[r * H + j] = o;
    }
    __syncthreads();

    const int tx = t & 31, ty = t >> 5;
    float acc[8][4] = {};
    mm_q(a_lds, w_lds, tx, ty, 0, acc);
#pragma unroll
    for (int q = 1; q < 4; ++q) {
        __syncthreads();
        stage_wq(w1 + q * 32 * H, w_lds, t);
        __syncthreads();
        mm_q(a_lds, w_lds, tx, ty, q * 32, acc);
    }
    __syncthreads();   // all reads of a_lds (and w_lds) done before overwrite

    // hid tile -> a_lds (relu(acc+b1)); stage w2 quarter 0
    {
        float4 bb1 = *(const float4*)&b1[tx * 4];
#pragma unroll
        for (int rr = 0; rr < 8; ++rr) {
            float4 o;
            o.x = fmaxf(acc[rr][0] + bb1.x, 0.f);
            o.y = fmaxf(acc[rr][1] + bb1.y, 0.f);
            o.z = fmaxf(acc[rr][2] + bb1.z, 0.f);
            o.w = fmaxf(acc[rr][3] + bb1.w, 0.f);
            *(float4*)&a_lds[(ty * 8 + rr) * H + tx * 4] = o;
        }
        stage_wq(w2, w_lds, t);
    }
    __syncthreads();

    float acc2[8][4] = {};
    mm_q(a_lds, w_lds, tx, ty, 0, acc2);
#pragma unroll
    for (int q = 1; q < 4; ++q) {
        __syncthreads();
        stage_wq(w2 + q * 32 * H, w_lds, t);
        __syncthreads();
        mm_q(a_lds, w_lds, tx, ty, q * 32, acc2);
    }

    float4 bb2 = *(const float4*)&b2[tx * 4];
#pragma unroll
    for (int rr = 0; rr < 8; ++rr) {
        int gr = row0 + ty * 8 + rr;
        bool ok = gr < nrows;
        float4 hres = {0.f, 0.f, 0.f, 0.f};
        if (ok) hres = *(const float4*)&h_in[(size_t)gr * H + tx * 4];
        float v0 = hres.x + fmaxf(acc2[rr][0] + bb2.x, 0.f);
        float v1 = hres.y + fmaxf(acc2[rr][1] + bb2.y, 0.f);
        float v2 = hres.z + fmaxf(acc2[rr][2] + bb2.z, 0.f);
        float v3 = hres.w + fmaxf(acc2[rr][3] + bb2.w, 0.f);
        float4 o = ln_vals(v0, v1, v2, v3, tx, g, be);
        if (ok) *(float4*)(h_out + (size_t)gr * H + tx * 4) = o;
    }
}

// ---------------- heads: GEMM-shaped, quarter-staged ----------------
// W = [dh_w1 | sh_w1] (128x128). Lanes tx<16 -> disp cols, tx>=16 -> stress.
__global__ __launch_bounds__(256, 3) void heads_kernel(
    const float* __restrict__ h,
    const float* __restrict__ dh_w1, const float* __restrict__ dh_b1,
    const float* __restrict__ dh_w2, const float* __restrict__ dh_b2,
    const float* __restrict__ sh_w1, const float* __restrict__ sh_b1,
    const float* __restrict__ sh_w2, const float* __restrict__ sh_b2,
    const float* __restrict__ lds_scalar, float* __restrict__ out, int nrows) {
    __shared__ float w_lds[32 * H];
    __shared__ float a_lds[64 * H];
    const int t = threadIdx.x;
    const int row0 = blockIdx.x * 64;

    auto stage_heads = [&](int k0) {   // stage combined-W rows k0..k0+31
#pragma unroll
        for (int i = 0; i < 4; ++i) {
            int idx = t * 4 + i * 1024;
            int kl = idx >> 7, c = idx & 127;
            const float* src = (c < 64) ? &dh_w1[(k0 + kl) * 64 + c]
                                        : &sh_w1[(k0 + kl) * 64 + (c - 64)];
            *(float4*)&w_lds[idx] = *(const float4*)src;
        }
    };
    stage_heads(0);
#pragma unroll
    for (int i = 0; i < 8; ++i) {
        int idx = t * 4 + i * 1024;
        int rrow = row0 + (idx >> 7);
        float4 v = {0.f, 0.f, 0.f, 0.f};
        if (rrow < nrows) v = *(const float4*)&h[(size_t)row0 * H + idx];
        *(float4*)&a_lds[idx] = v;
    }
    __syncthreads();
    const int tx = t & 31, ty = t >> 5;
    float acc[8][4] = {};
    mm_q(a_lds, w_lds, tx, ty, 0, acc);
#pragma unroll
    for (int q = 1; q < 4; ++q) {
        __syncthreads();
        stage_heads(q * 32);
        __syncthreads();
        mm_q(a_lds, w_lds, tx, ty, q * 32, acc);
    }

    const float ds = 0.001f + log1pf(expf(lds_scalar[0]));
    const bool isDisp = tx < 16;
    float b1v[4], w2v0[4], w2v1[4], w2v2[4];
#pragma unroll
    for (int cc = 0; cc < 4; ++cc) {
        int col = tx * 4 + cc;
        if (isDisp) {
            b1v[cc] = dh_b1[col];
            w2v0[cc] = dh_w2[col * 3 + 0];
            w2v1[cc] = dh_w2[col * 3 + 1];
            w2v2[cc] = dh_w2[col * 3 + 2];
        } else {
            b1v[cc] = sh_b1[col - 64];
            w2v0[cc] = sh_w2[col - 64];
            w2v1[cc] = 0.f;
            w2v2[cc] = 0.f;
        }
    }
#pragma unroll
    for (int rr = 0; rr < 8; ++rr) {
        int gr = row0 + ty * 8 + rr;
        float p0 = 0.f, p1 = 0.f, p2 = 0.f;
#pragma unroll
        for (int cc = 0; cc < 4; ++cc) {
            float hd = fmaxf(acc[rr][cc] + b1v[cc], 0.f);
            p0 = fmaf(hd, w2v0[cc], p0);
            p1 = fmaf(hd, w2v1[cc], p1);
            p2 = fmaf(hd, w2v2[cc], p2);
        }
#pragma unroll
        for (int m = 1; m < 16; m <<= 1) {
            p0 += __shfl_xor(p0, m, 64);
            p1 += __shfl_xor(p1, m, 64);
            p2 += __shfl_xor(p2, m, 64);
        }
        if ((tx & 15) == 0 && gr < nrows) {
            if (isDisp) {
                out[gr * 3 + 0] = (p0 + dh_b2[0]) * ds;
                out[gr * 3 + 1] = (p1 + dh_b2[1]) * ds;
                out[gr * 3 + 2] = (p2 + dh_b2[2]) * ds;
                if (gr == 0) out[250000] = ds;
            } else {
                float ls = fminf(fmaxf(p0 + sh_b2[0], 0.f), 30.f);
                float s = expf(ls);
                out[150000 + gr] = s;
                out[200000 + gr] = ls;
                out[250001 + gr] = 2.5e8f / (s + 1e-8f);
            }
        }
    }
}

// ---------------- launch ----------------
extern "C" void kernel_launch(void* const* d_in, const int* in_sizes, int n_in,
                              void* d_out, int out_size, void* d_ws, size_t ws_size,
                              hipStream_t stream) {
    if (ws_size < NEED16) return;  // diagnostic guard (capture-safe: ws_size const)

    const float* x         = (const float*)d_in[0];
    const float* edge_attr = (const float*)d_in[1];
    const int*   ei        = (const int*)d_in[2];
    const float* ne_w1 = (const float*)d_in[3];
    const float* ne_b1 = (const float*)d_in[4];
    const float* ne_w2 = (const float*)d_in[5];
    const float* ne_b2 = (const float*)d_in[6];
    const float* ne_g  = (const float*)d_in[7];
    const float* ne_be = (const float*)d_in[8];
    const float* ee_w1 = (const float*)d_in[9];
    const float* ee_b1 = (const float*)d_in[10];
    const float* ee_w2 = (const float*)d_in[11];
    const float* ee_b2 = (const float*)d_in[12];
    const float* ee_g  = (const float*)d_in[13];
    const float* ee_be = (const float*)d_in[14];
    const float* conv_w1 = (const float*)d_in[15];
    const float* conv_b1 = (const float*)d_in[16];
    const float* conv_w2 = (const float*)d_in[17];
    const float* conv_b2 = (const float*)d_in[18];
    const float* pn_g  = (const float*)d_in[19];
    const float* pn_be = (const float*)d_in[20];
    const float* dh_w1 = (const float*)d_in[21];
    const float* dh_b1 = (const float*)d_in[22];
    const float* dh_w2 = (const float*)d_in[23];
    const float* dh_b2 = (const float*)d_in[24];
    const float* sh_w1 = (const float*)d_in[25];
    const float* sh_b1 = (const float*)d_in[26];
    const float* sh_w2 = (const float*)d_in[27];
    const float* sh_b2 = (const float*)d_in[28];
    const float* ldsc  = (const float*)d_in[29];

    float* ws = (float*)d_ws;
    float* h0 = ws;
    float* h1 = ws + W_H1;
    int* row_ptr = (int*)(ws + W_RP);
    int* cursor  = (int*)(ws + W_CUR);
    int* col_e   = (int*)(ws + W_CE);
    int* col_s   = (int*)(ws + W_CS);
    void* ea     = (void*)(ws + W_EA);
    float* out = (float*)d_out;

    const bool use32 = ws_size >= NEED32;

    // CSR build
    hipMemsetAsync(cursor, 0, N_NODES * sizeof(int), stream);
    count_kernel<<<(N_EDGES + 255) / 256, 256, 0, stream>>>(ei, cursor);
    scan_kernel<<<1, 1024, 0, stream>>>(cursor, row_ptr);
    fill_kernel<<<(N_EDGES + 255) / 256, 256, 0, stream>>>(ei, cursor, col_e, col_s);

    // node encoder -> h0
    encoder_kernel<5, float><<<(N_NODES + 63) / 64, 256, 0, stream>>>(
        x, ne_w1, ne_b1, ne_w2, ne_b2, ne_g, ne_be, h0, N_NODES);

    if (use32) {
        encoder_kernel<6, float><<<N_EDGES / 64, 256, 0, stream>>>(
            edge_attr, ee_w1, ee_b1, ee_w2, ee_b2, ee_g, ee_be, (float*)ea, N_EDGES);
        float* hin = h0; float* hout = h1;
        for (int l = 0; l < 3; ++l) {
            conv_kernel<float><<<(N_NODES + 63) / 64, 256, 0, stream>>>(
                hin, (const float*)ea, row_ptr, col_e, col_s,
                conv_w1 + (size_t)l * H * H, conv_b1 + l * H,
                conv_w2 + (size_t)l * H * H, conv_b2 + l * H,
                pn_g + l * H, pn_be + l * H, hout, N_NODES);
            float* tmp = hin; hin = hout; hout = tmp;
        }
    } else {
        encoder_kernel<6, __half><<<N_EDGES / 64, 256, 0, stream>>>(
            edge_attr, ee_w1, ee_b1, ee_w2, ee_b2, ee_g, ee_be, (__half*)ea, N_EDGES);
        float* hin = h0; float* hout = h1;
        for (int l = 0; l < 3; ++l) {
            conv_kernel<__half><<<(N_NODES + 63) / 64, 256, 0, stream>>>(
                hin, (const __half*)ea, row_ptr, col_e, col_s,
                conv_w1 + (size_t)l * H * H, conv_b1 + l * H,
                conv_w2 + (size_t)l * H * H, conv_b2 + l * H,
                pn_g + l * H, pn_be + l * H, hout, N_NODES);
            float* tmp = hin; hin = hout; hout = tmp;
        }
    }

    // after 3 ping-pong layers the final h is h1
    heads_kernel<<<(N_NODES + 63) / 64, 256, 0, stream>>>(
        h1, dh_w1, dh_b1, dh_w2, dh_b2, sh_w1, sh_b1, sh_w2, sh_b2, ldsc, out, N_NODES);
}

// Round 12
// 2531.230 us; speedup vs baseline: 1.9713x; 1.9713x over previous
//
#include <hip/hip_runtime.h>
#include <hip/hip_bf16.h>
#include <hip/hip_fp16.h>
#include <type_traits>

#define N_NODES 50000
#define N_EDGES 600000
#define H 128

// ---------------- workspace layout (word offsets), ea LAST --------
constexpr size_t W_H1  = 6400000;
constexpr size_t W_RP  = 12800000;
constexpr size_t W_CUR = 12850004;
constexpr size_t W_CE  = 12900004;
constexpr size_t W_CS  = 13500004;
constexpr size_t W_EA  = 14100004;                       // *4B (16B aligned)
constexpr size_t NEED32 = (W_EA + (size_t)N_EDGES * H) * 4;        // 363.6 MB
constexpr size_t NEED16 = (W_EA + (size_t)N_EDGES * H / 2) * 4;    // 210.0 MB

// ---------------- CSR build ----------------
__global__ void count_kernel(const int* __restrict__ ei, int* __restrict__ cnt) {
    int e = blockIdx.x * blockDim.x + threadIdx.x;
    if (e < N_EDGES) atomicAdd(&cnt[ei[N_EDGES + e]], 1);
}

__global__ void scan_kernel(int* __restrict__ cursor, int* __restrict__ row_ptr) {
    __shared__ int wsum[16];
    __shared__ int wexc[16];
    __shared__ int s_total;
    const int t = threadIdx.x;
    const int lane = t & 63, wid = t >> 6;
    int carry = 0;
    if (t == 0) row_ptr[0] = 0;
    for (int base = 0; base < N_NODES; base += 1024) {
        int i = base + t;
        int v = (i < N_NODES) ? cursor[i] : 0;
        int x = v;
#pragma unroll
        for (int off = 1; off < 64; off <<= 1) {
            int y = __shfl_up(x, off, 64);
            if (lane >= off) x += y;
        }
        if (lane == 63) wsum[wid] = x;
        __syncthreads();
        if (wid == 0 && lane < 16) {
            int w = wsum[lane];
            int xs = w;
#pragma unroll
            for (int off = 1; off < 16; off <<= 1) {
                int y = __shfl_up(xs, off, 64);
                if (lane >= off) xs += y;
            }
            wexc[lane] = xs - w;
            if (lane == 15) s_total = xs;
        }
        __syncthreads();
        int incl = carry + wexc[wid] + x;
        if (i < N_NODES) {
            cursor[i] = incl - v;
            row_ptr[i + 1] = incl;
        }
        carry += s_total;
        __syncthreads();
    }
}

__global__ void fill_kernel(const int* __restrict__ ei, int* __restrict__ cursor,
                            int* __restrict__ col_e, int* __restrict__ col_s) {
    int e = blockIdx.x * blockDim.x + threadIdx.x;
    if (e < N_EDGES) {
        int d = ei[N_EDGES + e];
        int pos = atomicAdd(&cursor[d], 1);
        col_e[pos] = e;
        col_s[pos] = ei[e];
    }
}

// ---------------- GEMM core: 64 rows x 128 cols, K staged in 32-row quarters ----------
// a_lds: [64][128] (32KB); w_lds: [32][128] (16KB). Total 48KB -> 3 blocks/CU.
// Thread (tx=t&31 -> cols tx*4..+3, ty=t>>5 -> rows ty*8..+7), acc[8][4].
// ROUND-10 LESSON: preloading av[8] (+acc[8][4]) forced ~115 live VGPRs against an
// 84-reg allocator budget -> 9GB scratch spill traffic, 6.5x slower. This version
// keeps ONE av live (broadcast read, 2 addrs/wave) inside the rr loop: ~70 live regs.
__device__ __forceinline__ void mm_q(const float* __restrict__ a_lds,
                                     const float* __restrict__ w_lds,
                                     int tx, int ty, int k0, float acc[8][4]) {
#pragma unroll
    for (int k = 0; k < 32; k += 4) {
        float4 wv[4];
#pragma unroll
        for (int kk = 0; kk < 4; ++kk)
            wv[kk] = *(const float4*)&w_lds[(k + kk) * H + tx * 4];
#pragma unroll
        for (int rr = 0; rr < 8; ++rr) {
            float4 av = *(const float4*)&a_lds[(ty * 8 + rr) * H + k0 + k];
            acc[rr][0] = fmaf(av.x, wv[0].x, acc[rr][0]);
            acc[rr][1] = fmaf(av.x, wv[0].y, acc[rr][1]);
            acc[rr][2] = fmaf(av.x, wv[0].z, acc[rr][2]);
            acc[rr][3] = fmaf(av.x, wv[0].w, acc[rr][3]);
            acc[rr][0] = fmaf(av.y, wv[1].x, acc[rr][0]);
            acc[rr][1] = fmaf(av.y, wv[1].y, acc[rr][1]);
            acc[rr][2] = fmaf(av.y, wv[1].z, acc[rr][2]);
            acc[rr][3] = fmaf(av.y, wv[1].w, acc[rr][3]);
            acc[rr][0] = fmaf(av.z, wv[2].x, acc[rr][0]);
            acc[rr][1] = fmaf(av.z, wv[2].y, acc[rr][1]);
            acc[rr][2] = fmaf(av.z, wv[2].z, acc[rr][2]);
            acc[rr][3] = fmaf(av.z, wv[2].w, acc[rr][3]);
            acc[rr][0] = fmaf(av.w, wv[3].x, acc[rr][0]);
            acc[rr][1] = fmaf(av.w, wv[3].y, acc[rr][1]);
            acc[rr][2] = fmaf(av.w, wv[3].z, acc[rr][2]);
            acc[rr][3] = fmaf(av.w, wv[3].w, acc[rr][3]);
        }
    }
}

// stage 32 rows (16KB) of a [128-col] weight matrix into w_lds (4 float4/thread)
__device__ __forceinline__ void stage_wq(const float* __restrict__ wsrc,
                                         float* __restrict__ w_lds, int t) {
#pragma unroll
    for (int i = 0; i < 4; ++i)
        *(float4*)&w_lds[t * 4 + i * 1024] = *(const float4*)&wsrc[t * 4 + i * 1024];
}

// LayerNorm over one row spread across a 32-lane tx group (4 vals/lane).
// xor masks 1..16 keep lanes within their 32-lane half; call UNCONDITIONALLY.
__device__ __forceinline__ float4 ln_vals(float v0, float v1, float v2, float v3,
                                          int tx, const float* __restrict__ g,
                                          const float* __restrict__ be) {
    float sum = v0 + v1 + v2 + v3;
    float sq = v0 * v0 + v1 * v1 + v2 * v2 + v3 * v3;
#pragma unroll
    for (int m = 1; m < 32; m <<= 1) {
        sum += __shfl_xor(sum, m, 64);
        sq  += __shfl_xor(sq, m, 64);
    }
    float mean = sum * 0.0078125f;
    float var = sq * 0.0078125f - mean * mean;
    float rstd = rsqrtf(var + 1e-5f);
    float4 gv = *(const float4*)&g[tx * 4];
    float4 bv = *(const float4*)&be[tx * 4];
    float4 o;
    o.x = (v0 - mean) * rstd * gv.x + bv.x;
    o.y = (v1 - mean) * rstd * gv.y + bv.y;
    o.z = (v2 - mean) * rstd * gv.z + bv.z;
    o.w = (v3 - mean) * rstd * gv.w + bv.w;
    return o;
}

// ---------------- encoder: OUT = LN(relu(in@w1+b1)@w2+b2) ----------------
template <int IN_DIM, typename OUT_T>
__global__ __launch_bounds__(256) void encoder_kernel(
    const float* __restrict__ in, const float* __restrict__ w1,
    const float* __restrict__ b1, const float* __restrict__ w2,
    const float* __restrict__ b2, const float* __restrict__ g,
    const float* __restrict__ be, OUT_T* __restrict__ out,
    int nrows) {
    __shared__ float w_lds[32 * H];
    __shared__ float a_lds[64 * H];
    const int t = threadIdx.x;
    const int row0 = blockIdx.x * 64;

    stage_wq(w2, w_lds, t);             // w2 rows 0..31

    // hidden stage: column-per-thread (conflict-free LDS writes), 32 rows/thread
    {
        const int c = t & 127;
        const int rh = (t >> 7) * 32;
        const float bb1 = b1[c];
        float w1r[IN_DIM];
#pragma unroll
        for (int i = 0; i < IN_DIM; ++i)
            w1r[i] = w1[i * H + c];
#pragma unroll 4
        for (int rr = 0; rr < 32; ++rr) {
            int r = rh + rr;
            int grow = row0 + r;
            float acc = bb1;
            if (grow < nrows) {
#pragma unroll
                for (int i = 0; i < IN_DIM; ++i)
                    acc = fmaf(in[(size_t)grow * IN_DIM + i], w1r[i], acc);
            }
            a_lds[r * H + c] = fmaxf(acc, 0.f);
        }
    }
    __syncthreads();

    const int tx = t & 31, ty = t >> 5;
    float acc[8][4] = {};
    mm_q(a_lds, w_lds, tx, ty, 0, acc);
#pragma unroll
    for (int q = 1; q < 4; ++q) {
        __syncthreads();
        stage_wq(w2 + q * 32 * H, w_lds, t);
        __syncthreads();
        mm_q(a_lds, w_lds, tx, ty, q * 32, acc);
    }

    float4 bb = *(const float4*)&b2[tx * 4];
#pragma unroll
    for (int rr = 0; rr < 8; ++rr) {
        int gr = row0 + ty * 8 + rr;
        float4 o = ln_vals(acc[rr][0] + bb.x, acc[rr][1] + bb.y,
                           acc[rr][2] + bb.z, acc[rr][3] + bb.w, tx, g, be);
        if (gr < nrows) {
            if constexpr (std::is_same<OUT_T, float>::value) {
                *(float4*)(out + (size_t)gr * H + tx * 4) = o;
            } else {
                __half2* dp = (__half2*)(out + (size_t)gr * H + tx * 4);
                dp[0] = __floats2half2_rn(o.x, o.y);
                dp[1] = __floats2half2_rn(o.z, o.w);
            }
        }
    }
}

// ---------------- fused GINEConv layer ----------------
// a = h_in + sum_in relu(h_in[src]+ea[e]);  hid = relu(a@w1+b1) (in LDS)
// h_out = LN(h_in + relu(hid@w2+b2))
template <typename EA_T>
__global__ __launch_bounds__(256) void conv_kernel(
    const float* __restrict__ h_in, const EA_T* __restrict__ ea,
    const int* __restrict__ row_ptr, const int* __restrict__ col_e,
    const int* __restrict__ col_s,
    const float* __restrict__ w1, const float* __restrict__ b1,
    const float* __restrict__ w2, const float* __restrict__ b2,
    const float* __restrict__ g, const float* __restrict__ be,
    float* __restrict__ h_out, int nrows) {
    __shared__ float w_lds[32 * H];
    __shared__ float a_lds[64 * H];
    const int t = threadIdx.x;
    const int row0 = blockIdx.x * 64;

    stage_wq(w1, w_lds, t);             // w1 rows 0..31

    // gather: 8 nodes per pass (32 lanes x float4 per node), 8 passes
    const int j = (t & 31) * 4;
    for (int pass = 0; pass < 8; ++pass) {
        int r = pass * 8 + (t >> 5);
        int n = row0 + r;
        float ax = 0.f, ay = 0.f, az = 0.f, aw = 0.f;
        if (n < nrows) {
            int beg = row_ptr[n], end = row_ptr[n + 1];
            for (int p = beg; p < end; ++p) {
                int e = col_e[p];
                int s = col_s[p];
                float4 hv = *(const float4*)&h_in[s * H + j];
                float ex, ey, ez, ew;
                if constexpr (std::is_same<EA_T, float>::value) {
                    float4 ev = *(const float4*)(ea + (size_t)e * H + j);
                    ex = ev.x; ey = ev.y; ez = ev.z; ew = ev.w;
                } else {
                    const __half2* ep = (const __half2*)(ea + (size_t)e * H + j);
                    float2 e01 = __half22float2(ep[0]);
                    float2 e23 = __half22float2(ep[1]);
                    ex = e01.x; ey = e01.y; ez = e23.x; ew = e23.y;
                }
                ax += fmaxf(hv.x + ex, 0.f);
                ay += fmaxf(hv.y + ey, 0.f);
                az += fmaxf(hv.z + ez, 0.f);
                aw += fmaxf(hv.w + ew, 0.f);
            }
            float4 hn = *(const float4*)&h_in[n * H + j];
            ax += hn.x; ay += hn.y; az += hn.z; aw += hn.w;
        }
        float4 o = {ax, ay, az, aw};
        *(float4*)&a_lds[r * H + j] = o;
    }
    __syncthreads();

    const int tx = t & 31, ty = t >> 5;
    float acc[8][4] = {};
    mm_q(a_lds, w_lds, tx, ty, 0, acc);
#pragma unroll
    for (int q = 1; q < 4; ++q) {
        __syncthreads();
        stage_wq(w1 + q * 32 * H, w_lds, t);
        __syncthreads();
        mm_q(a_lds, w_lds, tx, ty, q * 32, acc);
    }
    __syncthreads();   // all reads of a_lds (and w_lds) done before overwrite

    // hid tile -> a_lds (relu(acc+b1)); stage w2 quarter 0
    {
        float4 bb1 = *(const float4*)&b1[tx * 4];
#pragma unroll
        for (int rr = 0; rr < 8; ++rr) {
            float4 o;
            o.x = fmaxf(acc[rr][0] + bb1.x, 0.f);
            o.y = fmaxf(acc[rr][1] + bb1.y, 0.f);
            o.z = fmaxf(acc[rr][2] + bb1.z, 0.f);
            o.w = fmaxf(acc[rr][3] + bb1.w, 0.f);
            *(float4*)&a_lds[(ty * 8 + rr) * H + tx * 4] = o;
        }
        stage_wq(w2, w_lds, t);
    }
    __syncthreads();

    float acc2[8][4] = {};
    mm_q(a_lds, w_lds, tx, ty, 0, acc2);
#pragma unroll
    for (int q = 1; q < 4; ++q) {
        __syncthreads();
        stage_wq(w2 + q * 32 * H, w_lds, t);
        __syncthreads();
        mm_q(a_lds, w_lds, tx, ty, q * 32, acc2);
    }

    float4 bb2 = *(const float4*)&b2[tx * 4];
#pragma unroll
    for (int rr = 0; rr < 8; ++rr) {
        int gr = row0 + ty * 8 + rr;
        bool ok = gr < nrows;
        float4 hres = {0.f, 0.f, 0.f, 0.f};
        if (ok) hres = *(const float4*)&h_in[(size_t)gr * H + tx * 4];
        float v0 = hres.x + fmaxf(acc2[rr][0] + bb2.x, 0.f);
        float v1 = hres.y + fmaxf(acc2[rr][1] + bb2.y, 0.f);
        float v2 = hres.z + fmaxf(acc2[rr][2] + bb2.z, 0.f);
        float v3 = hres.w + fmaxf(acc2[rr][3] + bb2.w, 0.f);
        float4 o = ln_vals(v0, v1, v2, v3, tx, g, be);
        if (ok) *(float4*)(h_out + (size_t)gr * H + tx * 4) = o;
    }
}

// ---------------- heads: GEMM-shaped, quarter-staged ----------------
// W = [dh_w1 | sh_w1] (128x128). Lanes tx<16 -> disp cols, tx>=16 -> stress.
__global__ __launch_bounds__(256) void heads_kernel(
    const float* __restrict__ h,
    const float* __restrict__ dh_w1, const float* __restrict__ dh_b1,
    const float* __restrict__ dh_w2, const float* __restrict__ dh_b2,
    const float* __restrict__ sh_w1, const float* __restrict__ sh_b1,
    const float* __restrict__ sh_w2, const float* __restrict__ sh_b2,
    const float* __restrict__ lds_scalar, float* __restrict__ out, int nrows) {
    __shared__ float w_lds[32 * H];
    __shared__ float a_lds[64 * H];
    const int t = threadIdx.x;
    const int row0 = blockIdx.x * 64;

    auto stage_heads = [&](int k0) {   // stage combined-W rows k0..k0+31
#pragma unroll
        for (int i = 0; i < 4; ++i) {
            int idx = t * 4 + i * 1024;
            int kl = idx >> 7, c = idx & 127;
            const float* src = (c < 64) ? &dh_w1[(k0 + kl) * 64 + c]
                                        : &sh_w1[(k0 + kl) * 64 + (c - 64)];
            *(float4*)&w_lds[idx] = *(const float4*)src;
        }
    };
    stage_heads(0);
#pragma unroll
    for (int i = 0; i < 8; ++i) {
        int idx = t * 4 + i * 1024;
        int rrow = row0 + (idx >> 7);
        float4 v = {0.f, 0.f, 0.f, 0.f};
        if (rrow < nrows) v = *(const float4*)&h[(size_t)row0 * H + idx];
        *(float4*)&a_lds[idx] = v;
    }
    __syncthreads();
    const int tx = t & 31, ty = t >> 5;
    float acc[8][4] = {};
    mm_q(a_lds, w_lds, tx, ty, 0, acc);
#pragma unroll
    for (int q = 1; q < 4; ++q) {
        __syncthreads();
        stage_heads(q * 32);
        __syncthreads();
        mm_q(a_lds, w_lds, tx, ty, q * 32, acc);
    }

    const float ds = 0.001f + log1pf(expf(lds_scalar[0]));
    const bool isDisp = tx < 16;
    float b1v[4], w2v0[4], w2v1[4], w2v2[4];
#pragma unroll
    for (int cc = 0; cc < 4; ++cc) {
        int col = tx * 4 + cc;
        if (isDisp) {
            b1v[cc] = dh_b1[col];
            w2v0[cc] = dh_w2[col * 3 + 0];
            w2v1[cc] = dh_w2[col * 3 + 1];
            w2v2[cc] = dh_w2[col * 3 + 2];
        } else {
            b1v[cc] = sh_b1[col - 64];
            w2v0[cc] = sh_w2[col - 64];
            w2v1[cc] = 0.f;
            w2v2[cc] = 0.f;
        }
    }
#pragma unroll
    for (int rr = 0; rr < 8; ++rr) {
        int gr = row0 + ty * 8 + rr;
        float p0 = 0.f, p1 = 0.f, p2 = 0.f;
#pragma unroll
        for (int cc = 0; cc < 4; ++cc) {
            float hd = fmaxf(acc[rr][cc] + b1v[cc], 0.f);
            p0 = fmaf(hd, w2v0[cc], p0);
            p1 = fmaf(hd, w2v1[cc], p1);
            p2 = fmaf(hd, w2v2[cc], p2);
        }
#pragma unroll
        for (int m = 1; m < 16; m <<= 1) {
            p0 += __shfl_xor(p0, m, 64);
            p1 += __shfl_xor(p1, m, 64);
            p2 += __shfl_xor(p2, m, 64);
        }
        if ((tx & 15) == 0 && gr < nrows) {
            if (isDisp) {
                out[gr * 3 + 0] = (p0 + dh_b2[0]) * ds;
                out[gr * 3 + 1] = (p1 + dh_b2[1]) * ds;
                out[gr * 3 + 2] = (p2 + dh_b2[2]) * ds;
                if (gr == 0) out[250000] = ds;
            } else {
                float ls = fminf(fmaxf(p0 + sh_b2[0], 0.f), 30.f);
                float s = expf(ls);
                out[150000 + gr] = s;
                out[200000 + gr] = ls;
                out[250001 + gr] = 2.5e8f / (s + 1e-8f);
            }
        }
    }
}

// ---------------- launch ----------------
extern "C" void kernel_launch(void* const* d_in, const int* in_sizes, int n_in,
                              void* d_out, int out_size, void* d_ws, size_t ws_size,
                              hipStream_t stream) {
    if (ws_size < NEED16) return;  // diagnostic guard (capture-safe: ws_size const)

    const float* x         = (const float*)d_in[0];
    const float* edge_attr = (const float*)d_in[1];
    const int*   ei        = (const int*)d_in[2];
    const float* ne_w1 = (const float*)d_in[3];
    const float* ne_b1 = (const float*)d_in[4];
    const float* ne_w2 = (const float*)d_in[5];
    const float* ne_b2 = (const float*)d_in[6];
    const float* ne_g  = (const float*)d_in[7];
    const float* ne_be = (const float*)d_in[8];
    const float* ee_w1 = (const float*)d_in[9];
    const float* ee_b1 = (const float*)d_in[10];
    const float* ee_w2 = (const float*)d_in[11];
    const float* ee_b2 = (const float*)d_in[12];
    const float* ee_g  = (const float*)d_in[13];
    const float* ee_be = (const float*)d_in[14];
    const float* conv_w1 = (const float*)d_in[15];
    const float* conv_b1 = (const float*)d_in[16];
    const float* conv_w2 = (const float*)d_in[17];
    const float* conv_b2 = (const float*)d_in[18];
    const float* pn_g  = (const float*)d_in[19];
    const float* pn_be = (const float*)d_in[20];
    const float* dh_w1 = (const float*)d_in[21];
    const float* dh_b1 = (const float*)d_in[22];
    const float* dh_w2 = (const float*)d_in[23];
    const float* dh_b2 = (const float*)d_in[24];
    const float* sh_w1 = (const float*)d_in[25];
    const float* sh_b1 = (const float*)d_in[26];
    const float* sh_w2 = (const float*)d_in[27];
    const float* sh_b2 = (const float*)d_in[28];
    const float* ldsc  = (const float*)d_in[29];

    float* ws = (float*)d_ws;
    float* h0 = ws;
    float* h1 = ws + W_H1;
    int* row_ptr = (int*)(ws + W_RP);
    int* cursor  = (int*)(ws + W_CUR);
    int* col_e   = (int*)(ws + W_CE);
    int* col_s   = (int*)(ws + W_CS);
    void* ea     = (void*)(ws + W_EA);
    float* out = (float*)d_out;

    const bool use32 = ws_size >= NEED32;

    // CSR build
    hipMemsetAsync(cursor, 0, N_NODES * sizeof(int), stream);
    count_kernel<<<(N_EDGES + 255) / 256, 256, 0, stream>>>(ei, cursor);
    scan_kernel<<<1, 1024, 0, stream>>>(cursor, row_ptr);
    fill_kernel<<<(N_EDGES + 255) / 256, 256, 0, stream>>>(ei, cursor, col_e, col_s);

    // node encoder -> h0
    encoder_kernel<5, float><<<(N_NODES + 63) / 64, 256, 0, stream>>>(
        x, ne_w1, ne_b1, ne_w2, ne_b2, ne_g, ne_be, h0, N_NODES);

    if (use32) {
        encoder_kernel<6, float><<<N_EDGES / 64, 256, 0, stream>>>(
            edge_attr, ee_w1, ee_b1, ee_w2, ee_b2, ee_g, ee_be, (float*)ea, N_EDGES);
        float* hin = h0; float* hout = h1;
        for (int l = 0; l < 3; ++l) {
            conv_kernel<float><<<(N_NODES + 63) / 64, 256, 0, stream>>>(
                hin, (const float*)ea, row_ptr, col_e, col_s,
                conv_w1 + (size_t)l * H * H, conv_b1 + l * H,
                conv_w2 + (size_t)l * H * H, conv_b2 + l * H,
                pn_g + l * H, pn_be + l * H, hout, N_NODES);
            float* tmp = hin; hin = hout; hout = tmp;
        }
    } else {
        encoder_kernel<6, __half><<<N_EDGES / 64, 256, 0, stream>>>(
            edge_attr, ee_w1, ee_b1, ee_w2, ee_b2, ee_g, ee_be, (__half*)ea, N_EDGES);
        float* hin = h0; float* hout = h1;
        for (int l = 0; l < 3; ++l) {
            conv_kernel<__half><<<(N_NODES + 63) / 64, 256, 0, stream>>>(
                hin, (const __half*)ea, row_ptr, col_e, col_s,
                conv_w1 + (size_t)l * H * H, conv_b1 + l * H,
                conv_w2 + (size_t)l * H * H, conv_b2 + l * H,
                pn_g + l * H, pn_be + l * H, hout, N_NODES);
            float* tmp = hin; hin = hout; hout = tmp;
        }
    }

    // after 3 ping-pong layers the final h is h1
    heads_kernel<<<(N_NODES + 63) / 64, 256, 0, stream>>>(
        h1, dh_w1, dh_b1, dh_w2, dh_b2, sh_w1, sh_b1, sh_w2, sh_b2, ldsc, out, N_NODES);
}